// Round 1
// baseline (31.389 us; speedup 1.0000x reference)
//
#include <hip/hip_runtime.h>

// Problem constants (fixed by reference): pred/target (8,3,224,224) fp32.
#define BINS   30
#define BATCH  8
#define ROW_N  150528            // 3*224*224 elements per batch row
#define ROW_N4 (ROW_N / 4)       // 37632 float4 per row
#define BPR    37                // blocks per row (37*256 threads, ~4 float4/thread)
#define NROWS  16                // 2 inputs * 8 batches

// K2 = -0.5 / delta^2 * log2(e) = -450 * 1.4426950408889634
#define K2 (-649.2627684000335f)

__global__ __launch_bounds__(256) void hsim_hist_kernel(
    const float* __restrict__ pred,
    const float* __restrict__ target,
    float* __restrict__ ghist)   // [2][BATCH][BINS]: pred at 0, target at 240
{
    const int row       = blockIdx.x / BPR;   // 0..15
    const int chunk     = blockIdx.x % BPR;
    const int input_sel = row >> 3;           // 0 = pred, 1 = target
    const int batch     = row & 7;

    const float4* src4 =
        (const float4*)((input_sel ? target : pred) + (size_t)batch * ROW_N);

    const float DELTA = 1.0f / 30.0f;

    float acc[BINS];
#pragma unroll
    for (int b = 0; b < BINS; ++b) acc[b] = 0.0f;

    for (int i = chunk * 256 + threadIdx.x; i < ROW_N4; i += BPR * 256) {
        float4 v = src4[i];
#pragma unroll
        for (int b = 0; b < BINS; ++b) {
            const float c  = (b + 0.5f) * DELTA;
            const float d0 = v.x - c;
            const float d1 = v.y - c;
            const float d2 = v.z - c;
            const float d3 = v.w - c;
            acc[b] += __builtin_amdgcn_exp2f(d0 * d0 * K2);
            acc[b] += __builtin_amdgcn_exp2f(d1 * d1 * K2);
            acc[b] += __builtin_amdgcn_exp2f(d2 * d2 * K2);
            acc[b] += __builtin_amdgcn_exp2f(d3 * d3 * K2);
        }
    }

    // Wave-level butterfly reduce each bin across 64 lanes.
#pragma unroll
    for (int b = 0; b < BINS; ++b) {
        float v = acc[b];
#pragma unroll
        for (int off = 32; off >= 1; off >>= 1)
            v += __shfl_xor(v, off, 64);
        acc[b] = v;
    }

    __shared__ float lhist[BINS];
    if (threadIdx.x < BINS) lhist[threadIdx.x] = 0.0f;
    __syncthreads();

    if ((threadIdx.x & 63) == 0) {   // one lane per wave (4 waves)
#pragma unroll
        for (int b = 0; b < BINS; ++b) atomicAdd(&lhist[b], acc[b]);
    }
    __syncthreads();

    if (threadIdx.x < BINS) {
        atomicAdd(&ghist[input_sel * (BATCH * BINS) + batch * BINS + threadIdx.x],
                  lhist[threadIdx.x]);
    }
}

__global__ __launch_bounds__(256) void hsim_score_kernel(
    const float* __restrict__ ghist, float* __restrict__ out)
{
    const int t = threadIdx.x;
    float term = 0.0f;
    if (t < BATCH * BINS) {
        const float p  = ghist[t];                 // pred hist
        const float tt = ghist[BATCH * BINS + t];  // target hist
        const float m  = fminf(p, tt);
        const float pd = (p == 0.0f) ? 1.0f : p;
        term = m / pd;
    }
#pragma unroll
    for (int off = 32; off >= 1; off >>= 1)
        term += __shfl_xor(term, off, 64);

    __shared__ float ws[4];
    if ((t & 63) == 0) ws[t >> 6] = term;
    __syncthreads();
    if (t == 0) {
        out[0] = (ws[0] + ws[1] + ws[2] + ws[3]) * (1.0f / (BATCH * BINS));
    }
}

extern "C" void kernel_launch(void* const* d_in, const int* in_sizes, int n_in,
                              void* d_out, int out_size, void* d_ws, size_t ws_size,
                              hipStream_t stream) {
    const float* pred   = (const float*)d_in[0];
    const float* target = (const float*)d_in[1];
    float*       ghist  = (float*)d_ws;     // 480 floats of scratch

    hipMemsetAsync(ghist, 0, 2 * BATCH * BINS * sizeof(float), stream);
    hsim_hist_kernel<<<NROWS * BPR, 256, 0, stream>>>(pred, target, ghist);
    hsim_score_kernel<<<1, 256, 0, stream>>>(ghist, (float*)d_out);
}

// Round 2
// 30.429 us; speedup vs baseline: 1.0316x; 1.0316x over previous
//
#include <hip/hip_runtime.h>

// Problem constants (fixed by reference): pred/target (8,3,224,224) fp32.
#define BINS   30
#define BATCH  8
#define ROW_N  150528            // 3*224*224 elements per batch row
#define ROW_N4 (ROW_N / 4)       // 37632 float4 per row
#define BPR    64                // blocks per row -> 1024 blocks, 4 waves/SIMD
#define NROWS  16                // 2 inputs * 8 batches

// K2 = -0.5 / delta^2 * log2(e) = -450 * log2(e)
#define K2D (-649.2627684000335)
#define K2F ((float)K2D)

__global__ __launch_bounds__(256) void hsim_hist_kernel(
    const float* __restrict__ pred,
    const float* __restrict__ target,
    float* __restrict__ ghist)   // [2][BATCH][BINS]: pred at 0, target at 240
{
    const int row       = blockIdx.x / BPR;   // 0..15
    const int chunk     = blockIdx.x % BPR;
    const int input_sel = row >> 3;           // 0 = pred, 1 = target
    const int batch     = row & 7;

    const float4* src4 =
        (const float4*)((input_sel ? target : pred) + (size_t)batch * ROW_N);

    float acc[BINS];
#pragma unroll
    for (int b = 0; b < BINS; ++b) acc[b] = 0.0f;

    for (int i = chunk * 256 + threadIdx.x; i < ROW_N4; i += BPR * 256) {
        float4 v = src4[i];
        // arg_b = K2*(x-c_b)^2 = K2*x^2 + P_b*x + Q_b  -> fma + add + exp + add
        const float X0 = (v.x * K2F) * v.x;
        const float X1 = (v.y * K2F) * v.y;
        const float X2 = (v.z * K2F) * v.z;
        const float X3 = (v.w * K2F) * v.w;
#pragma unroll
        for (int b = 0; b < BINS; ++b) {
            const double cd = (b + 0.5) / 30.0;
            const float  P  = (float)(-2.0 * K2D * cd);  // SGPR constant
            const float  Q  = (float)(K2D * cd * cd);    // literal
            acc[b] += __builtin_amdgcn_exp2f(fmaf(v.x, P, X0) + Q);
            acc[b] += __builtin_amdgcn_exp2f(fmaf(v.y, P, X1) + Q);
            acc[b] += __builtin_amdgcn_exp2f(fmaf(v.z, P, X2) + Q);
            acc[b] += __builtin_amdgcn_exp2f(fmaf(v.w, P, X3) + Q);
        }
    }

    // Wave-level butterfly reduce each bin across 64 lanes.
#pragma unroll
    for (int b = 0; b < BINS; ++b) {
        float v = acc[b];
#pragma unroll
        for (int off = 32; off >= 1; off >>= 1)
            v += __shfl_xor(v, off, 64);
        acc[b] = v;
    }

    __shared__ float lhist[BINS];
    if (threadIdx.x < BINS) lhist[threadIdx.x] = 0.0f;
    __syncthreads();

    if ((threadIdx.x & 63) == 0) {   // one lane per wave (4 waves)
#pragma unroll
        for (int b = 0; b < BINS; ++b) atomicAdd(&lhist[b], acc[b]);
    }
    __syncthreads();

    if (threadIdx.x < BINS) {
        atomicAdd(&ghist[input_sel * (BATCH * BINS) + batch * BINS + threadIdx.x],
                  lhist[threadIdx.x]);
    }
}

__global__ __launch_bounds__(256) void hsim_score_kernel(
    const float* __restrict__ ghist, float* __restrict__ out)
{
    const int t = threadIdx.x;
    float term = 0.0f;
    if (t < BATCH * BINS) {
        const float p  = ghist[t];                 // pred hist
        const float tt = ghist[BATCH * BINS + t];  // target hist
        const float m  = fminf(p, tt);
        const float pd = (p == 0.0f) ? 1.0f : p;
        term = m / pd;
    }
#pragma unroll
    for (int off = 32; off >= 1; off >>= 1)
        term += __shfl_xor(term, off, 64);

    __shared__ float ws[4];
    if ((t & 63) == 0) ws[t >> 6] = term;
    __syncthreads();
    if (t == 0) {
        out[0] = (ws[0] + ws[1] + ws[2] + ws[3]) * (1.0f / (BATCH * BINS));
    }
}

extern "C" void kernel_launch(void* const* d_in, const int* in_sizes, int n_in,
                              void* d_out, int out_size, void* d_ws, size_t ws_size,
                              hipStream_t stream) {
    const float* pred   = (const float*)d_in[0];
    const float* target = (const float*)d_in[1];
    float*       ghist  = (float*)d_ws;     // 480 floats of scratch

    hipMemsetAsync(ghist, 0, 2 * BATCH * BINS * sizeof(float), stream);
    hsim_hist_kernel<<<NROWS * BPR, 256, 0, stream>>>(pred, target, ghist);
    hsim_score_kernel<<<1, 256, 0, stream>>>(ghist, (float*)d_out);
}